// Round 1
// baseline (292.910 us; speedup 1.0000x reference)
//
#include <hip/hip_runtime.h>
#include <math.h>

#define IN_DIM 384
#define HID 16
#define NCLS 2
#define BN_EPS 1e-5f
#define MAXG 64

// ---------------- CSR build ----------------
__global__ void k_hist(const int* __restrict__ ei, int E, int* __restrict__ deg) {
    int stride = gridDim.x * blockDim.x;
    for (int e = blockIdx.x * blockDim.x + threadIdx.x; e < E; e += stride)
        atomicAdd(&deg[ei[e]], 1);
}

// Allocate contiguous CSR regions per node; region order across nodes is
// irrelevant, so a wave-level scan + one atomic per wave replaces a global scan.
__global__ void k_alloc(const int* __restrict__ deg, int N, int* __restrict__ offs,
                        int* __restrict__ wcur, int* __restrict__ cursor) {
    int i = blockIdx.x * blockDim.x + threadIdx.x;
    int lane = threadIdx.x & 63;
    int d = (i < N) ? deg[i] : 0;
    int run = d;
#pragma unroll
    for (int s = 1; s < 64; s <<= 1) {
        int v = __shfl_up(run, s, 64);
        if (lane >= s) run += v;
    }
    int total = __shfl(run, 63, 64);
    int base = 0;
    if (lane == 63) base = atomicAdd(cursor, total);
    base = __shfl(base, 63, 64);
    if (i < N) {
        int o = base + run - d;
        offs[i] = o;
        wcur[i] = o;
    }
}

__global__ void k_scatter(const int* __restrict__ ei, const int* __restrict__ ej, int E,
                          int* __restrict__ wcur, int* __restrict__ colidx) {
    int stride = gridDim.x * blockDim.x;
    for (int e = blockIdx.x * blockDim.x + threadIdx.x; e < E; e += stride) {
        int i = ei[e];
        int pos = atomicAdd(&wcur[i], 1);
        colidx[pos] = ej[e];
    }
}

// ---------------- per-node pre-projection: y[i][0..15]=x@W_mean.T, y[i][16..31]=x@W_root.T
__global__ __launch_bounds__(256) void k_proj(const float* __restrict__ x,
                                              const float* __restrict__ wl,
                                              const float* __restrict__ wr, int N,
                                              float* __restrict__ y) {
    int stride = gridDim.x * blockDim.x;
    for (int i = blockIdx.x * blockDim.x + threadIdx.x; i < N; i += stride) {
        const float4* xr = (const float4*)(x + (size_t)i * IN_DIM);
        float acc[32];
#pragma unroll
        for (int k = 0; k < 32; k++) acc[k] = 0.f;
        for (int m = 0; m < IN_DIM / 4; m++) {
            float4 v = xr[m];
#pragma unroll
            for (int k = 0; k < 16; k++) {
                const float* wm = wl + k * (2 * IN_DIM) + 4 * m;  // mean part of lin_l
                acc[k] = fmaf(v.x, wm[0], acc[k]);
                acc[k] = fmaf(v.y, wm[1], acc[k]);
                acc[k] = fmaf(v.z, wm[2], acc[k]);
                acc[k] = fmaf(v.w, wm[3], acc[k]);
            }
#pragma unroll
            for (int k = 0; k < 16; k++) {
                const float* wq = wr + k * IN_DIM + 4 * m;        // lin_r
                acc[16 + k] = fmaf(v.x, wq[0], acc[16 + k]);
                acc[16 + k] = fmaf(v.y, wq[1], acc[16 + k]);
                acc[16 + k] = fmaf(v.z, wq[2], acc[16 + k]);
                acc[16 + k] = fmaf(v.w, wq[3], acc[16 + k]);
            }
        }
        float* yo = y + (size_t)i * 32;
#pragma unroll
        for (int k = 0; k < 32; k++) yo[k] = acc[k];
    }
}

// ---------------- wave-per-node: gather neighbors, 384-dim max in regs,
// project max through W_max (LDS), add mean/root/bias -> h[N][16]
__global__ __launch_bounds__(256) void k_node(const float* __restrict__ x,
                                              const float* __restrict__ y,
                                              const float* __restrict__ wl,
                                              const float* __restrict__ lb,
                                              const int* __restrict__ deg,
                                              const int* __restrict__ offs,
                                              const int* __restrict__ colidx, int N,
                                              float* __restrict__ h) {
    __shared__ float shW[16 * 386];  // W_max padded stride 386 -> conflict-free reads
    for (int idx = threadIdx.x; idx < 16 * IN_DIM; idx += blockDim.x) {
        int k = idx / IN_DIM, d = idx % IN_DIM;
        shW[k * 386 + d] = wl[k * (2 * IN_DIM) + IN_DIM + d];
    }
    __syncthreads();
    int lane = threadIdx.x & 63;
    int wid = threadIdx.x >> 6;
    int wstride = gridDim.x * (blockDim.x >> 6);
    for (int i = blockIdx.x * (blockDim.x >> 6) + wid; i < N; i += wstride) {
        int dg = deg[i], beg = offs[i];
        float maxv[6];
#pragma unroll
        for (int m = 0; m < 6; m++) maxv[m] = -INFINITY;
        float s16 = 0.f;
        for (int e = 0; e < dg; e++) {
            int j = colidx[beg + e];
            const float* xr = x + (size_t)j * IN_DIM;
#pragma unroll
            for (int m = 0; m < 6; m++) maxv[m] = fmaxf(maxv[m], xr[m * 64 + lane]);
            if (lane < HID) s16 += y[(size_t)j * 32 + lane];
        }
        if (dg == 0) {  // wave-uniform; isolated node -> max_agg = 0
#pragma unroll
            for (int m = 0; m < 6; m++) maxv[m] = 0.f;
        }
        float p[16];
#pragma unroll
        for (int k = 0; k < 16; k++) {
            float t = 0.f;
#pragma unroll
            for (int m = 0; m < 6; m++)
                t = fmaf(maxv[m], shW[k * 386 + m * 64 + lane], t);
            p[k] = t;
        }
#pragma unroll
        for (int s = 1; s < 64; s <<= 1) {
#pragma unroll
            for (int k = 0; k < 16; k++) p[k] += __shfl_xor(p[k], s, 64);
        }
        if (lane < HID) {
            float pr = p[0];
#pragma unroll
            for (int k = 1; k < 16; k++) pr = (lane == k) ? p[k] : pr;
            float mean = s16 / (float)max(dg, 1);
            h[(size_t)i * HID + lane] = mean + pr + y[(size_t)i * 32 + 16 + lane] + lb[lane];
        }
    }
}

// ---------------- BN statistics (sum, sumsq per channel)
__global__ __launch_bounds__(256) void k_stats(const float* __restrict__ h, int N,
                                               float* __restrict__ stats) {
    __shared__ float sm[32];
    if (threadIdx.x < 32) sm[threadIdx.x] = 0.f;
    __syncthreads();
    int lane = threadIdx.x & 63;
    int c = lane & 15;
    int tot = N * HID;
    float s = 0.f, s2 = 0.f;
    int stride = gridDim.x * blockDim.x;
    for (int idx = blockIdx.x * blockDim.x + threadIdx.x; idx < tot; idx += stride) {
        float v = h[idx];  // idx%16 == lane%16 (blockDim, stride multiples of 16)
        s += v;
        s2 = fmaf(v, v, s2);
    }
    s += __shfl_xor(s, 16, 64);
    s += __shfl_xor(s, 32, 64);
    s2 += __shfl_xor(s2, 16, 64);
    s2 += __shfl_xor(s2, 32, 64);
    if (lane < 16) {
        atomicAdd(&sm[c], s);
        atomicAdd(&sm[16 + c], s2);
    }
    __syncthreads();
    if (threadIdx.x < 32) atomicAdd(&stats[threadIdx.x], sm[threadIdx.x]);
}

// ---------------- BN + ReLU + global mean pool (LDS pre-aggregation; batch sorted)
__global__ __launch_bounds__(256) void k_pool(const float* __restrict__ h,
                                              const int* __restrict__ batch,
                                              const float* __restrict__ stats,
                                              const float* __restrict__ gamma,
                                              const float* __restrict__ beta, int N,
                                              float* __restrict__ pooled,
                                              int* __restrict__ gcnt) {
    __shared__ float smP[MAXG * HID];
    __shared__ int smC[MAXG];
    for (int idx = threadIdx.x; idx < MAXG * HID; idx += blockDim.x) smP[idx] = 0.f;
    if (threadIdx.x < MAXG) smC[threadIdx.x] = 0;
    __syncthreads();
    int c = threadIdx.x & 15;
    float invN = 1.f / (float)N;
    float mu = stats[c] * invN;
    float var = stats[16 + c] * invN - mu * mu;
    float sc = gamma[c] * rsqrtf(var + BN_EPS);
    float sh = beta[c] - mu * sc;
    int base = blockIdx.x * 1024;
    int endn = min(base + 1024, N);
    for (int idx = base * HID + threadIdx.x; idx < endn * HID; idx += blockDim.x) {
        int n = idx >> 4;
        float v = fmaxf(fmaf(h[idx], sc, sh), 0.f);
        int g = batch[n] & (MAXG - 1);
        atomicAdd(&smP[g * HID + c], v);
        if (c == 0) atomicAdd(&smC[g], 1);
    }
    __syncthreads();
    for (int idx = threadIdx.x; idx < MAXG * HID; idx += blockDim.x)
        if (smP[idx] != 0.f) atomicAdd(&pooled[idx], smP[idx]);
    if (threadIdx.x < MAXG && smC[threadIdx.x]) atomicAdd(&gcnt[threadIdx.x], smC[threadIdx.x]);
}

// ---------------- pooled mean + FC
__global__ void k_final(const float* __restrict__ pooled, const int* __restrict__ gcnt,
                        const float* __restrict__ fcw, const float* __restrict__ fcb, int G,
                        float* __restrict__ out) {
    int g = threadIdx.x;
    if (g < G) {
        float inv = 1.f / (float)max(gcnt[g], 1);
        float o0 = fcb[0], o1 = fcb[1];
#pragma unroll
        for (int ch = 0; ch < HID; ch++) {
            float pv = pooled[g * HID + ch] * inv;
            o0 = fmaf(pv, fcw[ch], o0);
            o1 = fmaf(pv, fcw[HID + ch], o1);
        }
        out[g * NCLS + 0] = o0;
        out[g * NCLS + 1] = o1;
    }
}

extern "C" void kernel_launch(void* const* d_in, const int* in_sizes, int n_in,
                              void* d_out, int out_size, void* d_ws, size_t ws_size,
                              hipStream_t stream) {
    const float* x = (const float*)d_in[0];
    const int* ei = (const int*)d_in[1];           // edge_index[0] (targets i)
    const int* batch = (const int*)d_in[2];
    const float* wl = (const float*)d_in[4];       // lin_l_w [16][768]
    const float* lb = (const float*)d_in[5];       // lin_l_b [16]
    const float* wr = (const float*)d_in[6];       // lin_r_w [16][384]
    const float* gamma = (const float*)d_in[7];
    const float* beta = (const float*)d_in[8];
    const float* fcw = (const float*)d_in[9];      // fc_w [2][16]
    const float* fcb = (const float*)d_in[10];

    const int N = in_sizes[0] / IN_DIM;
    const int E = in_sizes[1] / 2;
    const int G = out_size / NCLS;
    const int* ej = ei + E;                        // edge_index[1] (sources j)

    // workspace layout
    size_t off = 0;
    auto take = [&](size_t b) { size_t r = off; off += (b + 255) & ~(size_t)255; return r; };
    size_t deg_off  = take((size_t)N * 4);
    size_t cur_off  = take(4);
    size_t stat_off = take(32 * 4);
    size_t pool_off = take((size_t)MAXG * HID * 4);
    size_t gcnt_off = take((size_t)MAXG * 4);
    size_t zero_bytes = off;                        // everything above must start at 0
    size_t offs_off = take((size_t)N * 4);
    size_t wcur_off = take((size_t)N * 4);
    size_t col_off  = take((size_t)E * 4);
    size_t y_off    = take((size_t)N * 32 * 4);
    size_t h_off    = take((size_t)N * HID * 4);
    (void)ws_size;

    char* ws = (char*)d_ws;
    int* deg = (int*)(ws + deg_off);
    int* cursor = (int*)(ws + cur_off);
    float* stats = (float*)(ws + stat_off);
    float* pooled = (float*)(ws + pool_off);
    int* gcnt = (int*)(ws + gcnt_off);
    int* offs = (int*)(ws + offs_off);
    int* wcur = (int*)(ws + wcur_off);
    int* colidx = (int*)(ws + col_off);
    float* y = (float*)(ws + y_off);
    float* h = (float*)(ws + h_off);

    hipMemsetAsync(d_ws, 0, zero_bytes, stream);

    int eblocks = (E + 255) / 256;
    k_hist<<<eblocks, 256, 0, stream>>>(ei, E, deg);
    k_alloc<<<(N + 255) / 256, 256, 0, stream>>>(deg, N, offs, wcur, cursor);
    k_scatter<<<eblocks, 256, 0, stream>>>(ei, ej, E, wcur, colidx);
    k_proj<<<(N + 255) / 256, 256, 0, stream>>>(x, wl, wr, N, y);
    k_node<<<2048, 256, 0, stream>>>(x, y, wl, lb, deg, offs, colidx, N, h);
    k_stats<<<256, 256, 0, stream>>>(h, N, stats);
    k_pool<<<(N + 1023) / 1024, 256, 0, stream>>>(h, batch, stats, gamma, beta, N, pooled, gcnt);
    k_final<<<1, 64, 0, stream>>>(pooled, gcnt, fcw, fcb, G, (float*)d_out);
}

// Round 2
// 203.935 us; speedup vs baseline: 1.4363x; 1.4363x over previous
//
#include <hip/hip_runtime.h>
#include <math.h>

#define IN_DIM 384
#define HID 16
#define NCLS 2
#define BN_EPS 1e-5f
#define MAXG 64

// ---------------- CSR build ----------------
__global__ void k_hist(const int* __restrict__ ei, int E, int* __restrict__ deg) {
    int stride = gridDim.x * blockDim.x;
    for (int e = blockIdx.x * blockDim.x + threadIdx.x; e < E; e += stride)
        atomicAdd(&deg[ei[e]], 1);
}

// Wave-scan allocation of CSR regions (region order across nodes irrelevant).
__global__ void k_alloc(const int* __restrict__ deg, int N, int* __restrict__ offs,
                        int* __restrict__ wcur, int* __restrict__ cursor) {
    int i = blockIdx.x * blockDim.x + threadIdx.x;
    int lane = threadIdx.x & 63;
    int d = (i < N) ? deg[i] : 0;
    int run = d;
#pragma unroll
    for (int s = 1; s < 64; s <<= 1) {
        int v = __shfl_up(run, s, 64);
        if (lane >= s) run += v;
    }
    int total = __shfl(run, 63, 64);
    int base = 0;
    if (lane == 63) base = atomicAdd(cursor, total);
    base = __shfl(base, 63, 64);
    if (i < N) {
        int o = base + run - d;
        offs[i] = o;
        wcur[i] = o;
    }
}

__global__ void k_scatter(const int* __restrict__ ei, const int* __restrict__ ej, int E,
                          int* __restrict__ wcur, int* __restrict__ colidx) {
    int stride = gridDim.x * blockDim.x;
    for (int e = blockIdx.x * blockDim.x + threadIdx.x; e < E; e += stride) {
        int i = ei[e];
        int pos = atomicAdd(&wcur[i], 1);
        colidx[pos] = ej[e];
    }
}

// ---------------- pre-projection y[i][0..15]=x@W_mean.T, y[i][16..31]=x@W_root.T
// Block = 4 waves x 64 lanes; lane = node within 64-node tile; wave = 8-row group.
// Weight addresses are wave-uniform -> scalar (SMEM) loads, VALU stays on FMAs.
__global__ __launch_bounds__(256) void k_proj(const float* __restrict__ x,
                                              const float* __restrict__ wl,
                                              const float* __restrict__ wr, int N,
                                              float* __restrict__ y) {
    int lane = threadIdx.x & 63;
    int wid = __builtin_amdgcn_readfirstlane(threadIdx.x >> 6);
    const float* wb = (wid < 2) ? (wl + wid * 8 * (2 * IN_DIM))
                                : (wr + (wid - 2) * 8 * IN_DIM);
    const int wstr = (wid < 2) ? (2 * IN_DIM) : IN_DIM;
    int i = blockIdx.x * 64 + lane;
    bool act = (i < N);
    const float4* xr = (const float4*)(x + (size_t)(act ? i : 0) * IN_DIM);
    float acc[8];
#pragma unroll
    for (int r = 0; r < 8; r++) acc[r] = 0.f;
    for (int m = 0; m < IN_DIM / 4; m++) {
        float4 v = xr[m];
#pragma unroll
        for (int r = 0; r < 8; r++) {
            const float4 w = *(const float4*)(wb + r * wstr + 4 * m);
            acc[r] = fmaf(v.x, w.x, acc[r]);
            acc[r] = fmaf(v.y, w.y, acc[r]);
            acc[r] = fmaf(v.z, w.z, acc[r]);
            acc[r] = fmaf(v.w, w.w, acc[r]);
        }
    }
    if (act) {
        float* yo = y + (size_t)i * 32 + wid * 8;
        ((float4*)yo)[0] = make_float4(acc[0], acc[1], acc[2], acc[3]);
        ((float4*)yo)[1] = make_float4(acc[4], acc[5], acc[6], acc[7]);
    }
}

// ---------------- wave-per-node: gather neighbors (4-edge chunks for MLP),
// 384-dim running max as 3x float2/lane, project through W_max (LDS),
// add mean/root/bias -> h[N][16]; fused BN-stats accumulation.
__global__ __launch_bounds__(256) void k_node(const float* __restrict__ x,
                                              const float* __restrict__ y,
                                              const float* __restrict__ wl,
                                              const float* __restrict__ lb,
                                              const int* __restrict__ deg,
                                              const int* __restrict__ offs,
                                              const int* __restrict__ colidx, int N,
                                              float* __restrict__ h,
                                              float* __restrict__ stats) {
    __shared__ float shW[16 * 388];  // stride 388 -> float2 reads 8B-aligned, conflict-free
    __shared__ float shS[32];
    for (int idx = threadIdx.x; idx < 16 * IN_DIM; idx += blockDim.x) {
        int k = idx / IN_DIM, d = idx - k * IN_DIM;
        shW[k * 388 + d] = wl[k * (2 * IN_DIM) + IN_DIM + d];
    }
    if (threadIdx.x < 32) shS[threadIdx.x] = 0.f;
    __syncthreads();
    int lane = threadIdx.x & 63;
    int wid = threadIdx.x >> 6;
    int wstride = gridDim.x * 4;
    float sAcc = 0.f, s2Acc = 0.f;
    for (int i = blockIdx.x * 4 + wid; i < N; i += wstride) {
        int dg = deg[i], beg = offs[i];
        float2 mx0 = make_float2(-INFINITY, -INFINITY), mx1 = mx0, mx2 = mx0;
        float s16 = 0.f;
        for (int e0 = 0; e0 < dg; e0 += 64) {
            int nv = min(64, dg - e0);
            int jv = (lane < nv) ? colidx[beg + e0 + lane] : 0;
            int eb = 0;
            for (; eb + 4 <= nv; eb += 4) {
                int j0 = __shfl(jv, eb, 64), j1 = __shfl(jv, eb + 1, 64);
                int j2 = __shfl(jv, eb + 2, 64), j3 = __shfl(jv, eb + 3, 64);
                const float2* p0 = (const float2*)(x + (size_t)j0 * IN_DIM);
                const float2* p1 = (const float2*)(x + (size_t)j1 * IN_DIM);
                const float2* p2 = (const float2*)(x + (size_t)j2 * IN_DIM);
                const float2* p3 = (const float2*)(x + (size_t)j3 * IN_DIM);
                float2 a00 = p0[lane], a01 = p0[64 + lane], a02 = p0[128 + lane];
                float2 a10 = p1[lane], a11 = p1[64 + lane], a12 = p1[128 + lane];
                float2 a20 = p2[lane], a21 = p2[64 + lane], a22 = p2[128 + lane];
                float2 a30 = p3[lane], a31 = p3[64 + lane], a32 = p3[128 + lane];
                float ym = 0.f;
                if (lane < HID) {
                    ym = y[(size_t)j0 * 32 + lane] + y[(size_t)j1 * 32 + lane] +
                         y[(size_t)j2 * 32 + lane] + y[(size_t)j3 * 32 + lane];
                }
                s16 += ym;
                mx0.x = fmaxf(fmaxf(mx0.x, fmaxf(a00.x, a10.x)), fmaxf(a20.x, a30.x));
                mx0.y = fmaxf(fmaxf(mx0.y, fmaxf(a00.y, a10.y)), fmaxf(a20.y, a30.y));
                mx1.x = fmaxf(fmaxf(mx1.x, fmaxf(a01.x, a11.x)), fmaxf(a21.x, a31.x));
                mx1.y = fmaxf(fmaxf(mx1.y, fmaxf(a01.y, a11.y)), fmaxf(a21.y, a31.y));
                mx2.x = fmaxf(fmaxf(mx2.x, fmaxf(a02.x, a12.x)), fmaxf(a22.x, a32.x));
                mx2.y = fmaxf(fmaxf(mx2.y, fmaxf(a02.y, a12.y)), fmaxf(a22.y, a32.y));
            }
            for (; eb < nv; eb++) {
                int j = __shfl(jv, eb, 64);
                const float2* p = (const float2*)(x + (size_t)j * IN_DIM);
                float2 a0 = p[lane], a1 = p[64 + lane], a2 = p[128 + lane];
                if (lane < HID) s16 += y[(size_t)j * 32 + lane];
                mx0.x = fmaxf(mx0.x, a0.x); mx0.y = fmaxf(mx0.y, a0.y);
                mx1.x = fmaxf(mx1.x, a1.x); mx1.y = fmaxf(mx1.y, a1.y);
                mx2.x = fmaxf(mx2.x, a2.x); mx2.y = fmaxf(mx2.y, a2.y);
            }
        }
        if (dg == 0) {  // wave-uniform; isolated node -> max_agg = 0
            mx0 = make_float2(0.f, 0.f); mx1 = mx0; mx2 = mx0;
        }
        float p[16];
#pragma unroll
        for (int k = 0; k < 16; k++) {
            const float2* wrow = (const float2*)(shW + k * 388);
            float2 w0 = wrow[lane], w1 = wrow[64 + lane], w2 = wrow[128 + lane];
            float t = mx0.x * w0.x;
            t = fmaf(mx0.y, w0.y, t);
            t = fmaf(mx1.x, w1.x, t);
            t = fmaf(mx1.y, w1.y, t);
            t = fmaf(mx2.x, w2.x, t);
            t = fmaf(mx2.y, w2.y, t);
            p[k] = t;
        }
#pragma unroll
        for (int st = 1; st < 64; st <<= 1) {
#pragma unroll
            for (int k = 0; k < 16; k++) p[k] += __shfl_xor(p[k], st, 64);
        }
        if (lane < HID) {
            float pr = p[0];
#pragma unroll
            for (int k = 1; k < 16; k++) pr = (lane == k) ? p[k] : pr;
            float hv = s16 / (float)max(dg, 1) + pr + y[(size_t)i * 32 + 16 + lane] + lb[lane];
            h[(size_t)i * HID + lane] = hv;
            sAcc += hv;
            s2Acc = fmaf(hv, hv, s2Acc);
        }
    }
    __syncthreads();
    if (lane < HID) {
        atomicAdd(&shS[lane], sAcc);
        atomicAdd(&shS[16 + lane], s2Acc);
    }
    __syncthreads();
    if (threadIdx.x < 32) atomicAdd(&stats[threadIdx.x], shS[threadIdx.x]);
}

// ---------------- BN + ReLU + global mean pool (LDS pre-aggregation; batch sorted)
__global__ __launch_bounds__(256) void k_pool(const float* __restrict__ h,
                                              const int* __restrict__ batch,
                                              const float* __restrict__ stats,
                                              const float* __restrict__ gamma,
                                              const float* __restrict__ beta, int N,
                                              float* __restrict__ pooled,
                                              int* __restrict__ gcnt) {
    __shared__ float smP[MAXG * HID];
    __shared__ int smC[MAXG];
    for (int idx = threadIdx.x; idx < MAXG * HID; idx += blockDim.x) smP[idx] = 0.f;
    if (threadIdx.x < MAXG) smC[threadIdx.x] = 0;
    __syncthreads();
    int c = threadIdx.x & 15;
    float invN = 1.f / (float)N;
    float mu = stats[c] * invN;
    float var = stats[16 + c] * invN - mu * mu;
    float sc = gamma[c] * rsqrtf(var + BN_EPS);
    float sh = beta[c] - mu * sc;
    int base = blockIdx.x * 1024;
    int endn = min(base + 1024, N);
    for (int idx = base * HID + threadIdx.x; idx < endn * HID; idx += blockDim.x) {
        int n = idx >> 4;
        float v = fmaxf(fmaf(h[idx], sc, sh), 0.f);
        int g = batch[n] & (MAXG - 1);
        atomicAdd(&smP[g * HID + c], v);
        if (c == 0) atomicAdd(&smC[g], 1);
    }
    __syncthreads();
    for (int idx = threadIdx.x; idx < MAXG * HID; idx += blockDim.x)
        if (smP[idx] != 0.f) atomicAdd(&pooled[idx], smP[idx]);
    if (threadIdx.x < MAXG && smC[threadIdx.x]) atomicAdd(&gcnt[threadIdx.x], smC[threadIdx.x]);
}

// ---------------- pooled mean + FC
__global__ void k_final(const float* __restrict__ pooled, const int* __restrict__ gcnt,
                        const float* __restrict__ fcw, const float* __restrict__ fcb, int G,
                        float* __restrict__ out) {
    int g = threadIdx.x;
    if (g < G) {
        float inv = 1.f / (float)max(gcnt[g], 1);
        float o0 = fcb[0], o1 = fcb[1];
#pragma unroll
        for (int ch = 0; ch < HID; ch++) {
            float pv = pooled[g * HID + ch] * inv;
            o0 = fmaf(pv, fcw[ch], o0);
            o1 = fmaf(pv, fcw[HID + ch], o1);
        }
        out[g * NCLS + 0] = o0;
        out[g * NCLS + 1] = o1;
    }
}

extern "C" void kernel_launch(void* const* d_in, const int* in_sizes, int n_in,
                              void* d_out, int out_size, void* d_ws, size_t ws_size,
                              hipStream_t stream) {
    const float* x = (const float*)d_in[0];
    const int* ei = (const int*)d_in[1];
    const int* batch = (const int*)d_in[2];
    const float* wl = (const float*)d_in[4];
    const float* lb = (const float*)d_in[5];
    const float* wr = (const float*)d_in[6];
    const float* gamma = (const float*)d_in[7];
    const float* beta = (const float*)d_in[8];
    const float* fcw = (const float*)d_in[9];
    const float* fcb = (const float*)d_in[10];

    const int N = in_sizes[0] / IN_DIM;
    const int E = in_sizes[1] / 2;
    const int G = out_size / NCLS;
    const int* ej = ei + E;

    size_t off = 0;
    auto take = [&](size_t b) { size_t r = off; off += (b + 255) & ~(size_t)255; return r; };
    size_t deg_off  = take((size_t)N * 4);
    size_t cur_off  = take(4);
    size_t stat_off = take(32 * 4);
    size_t pool_off = take((size_t)MAXG * HID * 4);
    size_t gcnt_off = take((size_t)MAXG * 4);
    size_t zero_bytes = off;
    size_t offs_off = take((size_t)N * 4);
    size_t wcur_off = take((size_t)N * 4);
    size_t col_off  = take((size_t)E * 4);
    size_t y_off    = take((size_t)N * 32 * 4);
    size_t h_off    = take((size_t)N * HID * 4);
    (void)ws_size;

    char* ws = (char*)d_ws;
    int* deg = (int*)(ws + deg_off);
    int* cursor = (int*)(ws + cur_off);
    float* stats = (float*)(ws + stat_off);
    float* pooled = (float*)(ws + pool_off);
    int* gcnt = (int*)(ws + gcnt_off);
    int* offs = (int*)(ws + offs_off);
    int* wcur = (int*)(ws + wcur_off);
    int* colidx = (int*)(ws + col_off);
    float* y = (float*)(ws + y_off);
    float* h = (float*)(ws + h_off);

    hipMemsetAsync(d_ws, 0, zero_bytes, stream);

    int eblocks = (E + 255) / 256;
    k_hist<<<eblocks, 256, 0, stream>>>(ei, E, deg);
    k_alloc<<<(N + 255) / 256, 256, 0, stream>>>(deg, N, offs, wcur, cursor);
    k_scatter<<<eblocks, 256, 0, stream>>>(ei, ej, E, wcur, colidx);
    k_proj<<<(N + 63) / 64, 256, 0, stream>>>(x, wl, wr, N, y);
    k_node<<<1536, 256, 0, stream>>>(x, y, wl, lb, deg, offs, colidx, N, h, stats);
    k_pool<<<(N + 1023) / 1024, 256, 0, stream>>>(h, batch, stats, gamma, beta, N, pooled, gcnt);
    k_final<<<1, 64, 0, stream>>>(pooled, gcnt, fcw, fcb, G, (float*)d_out);
}